// Round 14
// baseline (52.756 us; speedup 1.0000x reference)
//
#include <hip/hip_runtime.h>
#include <math.h>

#define NB 16
#define DM 128
#define BM 1024      // one block per CU: 16 waves resident
#define ZSTRIDE 68   // halves per Z row: 136 B (8B-aligned b64 access, bank-spread)

typedef _Float16 half8  __attribute__((ext_vector_type(8)));
typedef _Float16 half4v __attribute__((ext_vector_type(4)));
typedef _Float16 half2v __attribute__((ext_vector_type(2)));
typedef __fp16   fp16x2 __attribute__((ext_vector_type(2)));
typedef float    f32x4  __attribute__((ext_vector_type(4)));

__device__ __forceinline__ float frcp_(float x) { return __builtin_amdgcn_rcpf(x); }
__device__ __forceinline__ float softplus_fast(float x) {
    return fmaxf(x, 0.0f) + __logf(1.0f + __expf(-fabsf(x)));
}
__device__ __forceinline__ float sigmoid_fast(float x) {
    return frcp_(1.0f + __expf(-x));
}
__device__ __forceinline__ void softmax16_m(float* z) {
    float m = z[0];
#pragma unroll
    for (int k = 1; k < NB; k++) m = fmaxf(m, z[k]);
    float s = 0.0f;
#pragma unroll
    for (int k = 0; k < NB; k++) { z[k] = __expf(z[k] - m); s += z[k]; }
    float r = frcp_(s);
#pragma unroll
    for (int k = 0; k < NB; k++) z[k] *= r;
}
// outer softmax: inputs in [0,1] (inner softmax output) -> no max-subtract
__device__ __forceinline__ void softmax16_nm(float* z) {
    float s = 0.0f;
#pragma unroll
    for (int k = 0; k < NB; k++) { z[k] = __expf(z[k]); s += z[k]; }
    float r = frcp_(s);
#pragma unroll
    for (int k = 0; k < NB; k++) z[k] *= r;
}

__device__ __forceinline__ half2v pk_(float lo, float hi) {
    fp16x2 p = __builtin_amdgcn_cvt_pkrtz(lo, hi);
    return __builtin_bit_cast(half2v, p);
}
__device__ __forceinline__ half8 cvt8(float4 a0, float4 a1) {
    half2v p0 = pk_(a0.x, a0.y);
    half2v p1 = pk_(a0.z, a0.w);
    half2v p2 = pk_(a1.x, a1.y);
    half2v p3 = pk_(a1.z, a1.w);
    half8 f;
    f[0] = p0[0]; f[1] = p0[1]; f[2] = p1[0]; f[3] = p1[1];
    f[4] = p2[0]; f[5] = p2[1]; f[6] = p3[0]; f[7] = p3[1];
    return f;
}

// ---- named-variable macros (NO addressable aggregates; rule #20) ----
// Full-line pattern: instruction j reads 16 rows x one FULL 64B line each.
// Fragment slot formula (A and B IDENTICAL => HW k-permutation cancels):
//   frag s, elem e: k = 32s + 16*(e>=4) + lg*4 + (e&3)
#define LOADC(P, cr)                                    \
    P##0 = *(const float4*)((cr) + 0);                  \
    P##1 = *(const float4*)((cr) + 16);                 \
    P##2 = *(const float4*)((cr) + 32);                 \
    P##3 = *(const float4*)((cr) + 48);                 \
    P##4 = *(const float4*)((cr) + 64);                 \
    P##5 = *(const float4*)((cr) + 80);                 \
    P##6 = *(const float4*)((cr) + 96);                 \
    P##7 = *(const float4*)((cr) + 112);

#define CVTC(P)                                         \
    af0 = cvt8(P##0, P##1);                             \
    af1 = cvt8(P##2, P##3);                             \
    af2 = cvt8(P##4, P##5);                             \
    af3 = cvt8(P##6, P##7);

// B frags live in LDS, fragment-major: frag (t,s) of lane at
// byte offset ((t*4+s)*64 + lane)*16 -> one ds_read_b128, 2-way aliasing (free)
#define MFMA_GRP(af, s) {                                                       \
    const half8 bt0 = *(const half8*)(Blds + (((0*4+(s))*64 + lane) * 8));      \
    const half8 bt1 = *(const half8*)(Blds + (((1*4+(s))*64 + lane) * 8));      \
    const half8 bt2 = *(const half8*)(Blds + (((2*4+(s))*64 + lane) * 8));      \
    const half8 bt3 = *(const half8*)(Blds + (((3*4+(s))*64 + lane) * 8));      \
    acc0 = __builtin_amdgcn_mfma_f32_16x16x32_f16(af, bt0, acc0, 0, 0, 0);      \
    acc1 = __builtin_amdgcn_mfma_f32_16x16x32_f16(af, bt1, acc1, 0, 0, 0);      \
    acc2 = __builtin_amdgcn_mfma_f32_16x16x32_f16(af, bt2, acc2, 0, 0, 0);      \
    acc3 = __builtin_amdgcn_mfma_f32_16x16x32_f16(af, bt3, acc3, 0, 0, 0);      \
}

// D layout: col = lane&15, row = (lane>>4)*4 + reg  [m89/m91]
// interleaved Z: pos = col*4 + t  <=>  net n = t*16 + col
#define STOREZ(c) {                                                             \
    _Float16* zpw = zbase + (size_t)((c) * 16) * ZSTRIDE;                       \
    _Pragma("unroll")                                                           \
    for (int r = 0; r < 4; r++) {                                               \
        half2v p0 = pk_(acc0[r], acc1[r]);                                      \
        half2v p1 = pk_(acc2[r], acc3[r]);                                      \
        half4v w; w[0] = p0[0]; w[1] = p0[1]; w[2] = p1[0]; w[3] = p1[1];       \
        *(half4v*)(zpw + (size_t)r * ZSTRIDE) = w;                              \
    } }

#define RESET_ACC  acc0 = zf4; acc1 = zf4; acc2 = zf4; acc3 = zf4;

#define GEMM_CHUNK(P, c)                                                        \
    CVTC(P)                                                                     \
    MFMA_GRP(af0, 0) MFMA_GRP(af1, 1) MFMA_GRP(af2, 2) MFMA_GRP(af3, 3)         \
    STOREZ(c) RESET_ACC

// B staging: wave w (w<4) computes frags of matrix t=w and parks in LDS.
#define STAGE_B_LDS(Wt, isWd) {                                                 \
    const bool val = (!(isWd)) || (l15 < 15);                                   \
    const float* srcl = (Wt) + (size_t)(val ? l15 : 0) * DM + lg * 4;           \
    float4 q0 = *(const float4*)(srcl + 0),  q1 = *(const float4*)(srcl + 16);  \
    float4 q2 = *(const float4*)(srcl + 32), q3 = *(const float4*)(srcl + 48);  \
    float4 q4 = *(const float4*)(srcl + 64), q5 = *(const float4*)(srcl + 80);  \
    float4 q6 = *(const float4*)(srcl + 96), q7 = *(const float4*)(srcl + 112); \
    half8 Q0 = val ? cvt8(q0, q1) : hz;                                         \
    half8 Q1 = val ? cvt8(q2, q3) : hz;                                         \
    half8 Q2 = val ? cvt8(q4, q5) : hz;                                         \
    half8 Q3 = val ? cvt8(q6, q7) : hz;                                         \
    *(half8*)(Blds + (((wave*4+0)*64 + lane) * 8)) = Q0;                        \
    *(half8*)(Blds + (((wave*4+1)*64 + lane) * 8)) = Q1;                        \
    *(half8*)(Blds + (((wave*4+2)*64 + lane) * 8)) = Q2;                        \
    *(half8*)(Blds + (((wave*4+3)*64 + lane) * 8)) = Q3;                        \
}

// rule #18: inline-asm lgkm drain needs sched_barrier fencing
#define FENCE_LDS                                       \
    __builtin_amdgcn_sched_barrier(0);                  \
    asm volatile("s_waitcnt lgkmcnt(0)" ::: "memory");  \
    __builtin_amdgcn_sched_barrier(0);

// clamped row pointer for chunk c of this block's tile
#define CPTR(c) (cond + (((bRow + (size_t)(wave * 64 + (c) * 16 + l15)) < (size_t)N) \
                    ? (bRow + (size_t)(wave * 64 + (c) * 16 + l15))                  \
                    : ((size_t)N - 1)) * DM + lg * 4)

// ---- spline epilogue, streaming cw/ch + fused gather (register-slim;
// correctness-proven in R9: absmax 0.03125) ----
#define EPILOGUE(xv, giv)                                                        \
  if ((giv) < (size_t)N) {                                                       \
    float zw[NB], zh[NB], zl[NB], zd[NB - 1];                                    \
    const half4v* zr4 = (const half4v*)&Z[(size_t)tid * ZSTRIDE];                \
    _Pragma("unroll")                                                            \
    for (int j = 0; j < NB; j++) {                                               \
        half4v v = zr4[j];                                                       \
        zw[j] = (float)v[0] + bw[j];                                             \
        zh[j] = (float)v[1] + bh[j];                                             \
        zl[j] = (float)v[2] + bl[j];                                             \
        if (j < NB - 1) zd[j] = (float)v[3] + bd[j];                             \
    }                                                                            \
    float xc = fminf(fmaxf((xv), -20.0f), 20.0f);                                \
    softmax16_m(zw); softmax16_nm(zw);                                           \
    softmax16_m(zh); softmax16_nm(zh);                                           \
    const float scale = (1.0f - 1e-3f * NB);                                     \
    float cum_w = 1e-3f + scale * zw[0];                                         \
    float cum_h = 1e-3f + scale * zh[0];                                         \
    float cw_k1 = 40.0f * cum_w - 20.0f;  /* cw[1] */                            \
    float ch_k1 = 40.0f * cum_h - 20.0f;                                         \
    const float cw1 = cw_k1;                                                     \
    float in_cw = -20.0f, cw_hi = cw_k1, in_ch = -20.0f, ch_hi = ch_k1;          \
    float zl_sel = zl[0], zd_lo = zd[0], zd_hi = zd[0];                          \
    bool lastbin = false;                                                        \
    _Pragma("unroll")                                                            \
    for (int k = 1; k < NB; k++) {                                               \
        cum_w += 1e-3f + scale * zw[k];                                          \
        cum_h += 1e-3f + scale * zh[k];                                          \
        float cw_k2 = (k == NB - 1) ? 20.0f : (40.0f * cum_w - 20.0f);           \
        float ch_k2 = (k == NB - 1) ? 20.0f : (40.0f * cum_h - 20.0f);           \
        bool take = (xc >= cw_k1);      /* xc >= cw[k] */                        \
        in_cw  = take ? cw_k1 : in_cw;                                           \
        cw_hi  = take ? cw_k2 : cw_hi;                                           \
        in_ch  = take ? ch_k1 : in_ch;                                           \
        ch_hi  = take ? ch_k2 : ch_hi;                                           \
        zl_sel = take ? zl[k] : zl_sel;                                          \
        zd_lo  = take ? zd[k - 1] : zd_lo;                                       \
        zd_hi  = take ? zd[(k < NB - 1) ? k : NB - 2] : zd_hi;                   \
        if (k == NB - 1) lastbin = take;                                         \
        cw_k1 = cw_k2; ch_k1 = ch_k2;                                            \
    }                                                                            \
    bool firstbin = (xc < cw1);                                                  \
    float in_bw = cw_hi - in_cw;                                                 \
    float in_h  = ch_hi - in_ch;                                                 \
    float dk  = firstbin ? 1.0f : (1e-3f + softplus_fast(softplus_fast(zd_lo))); \
    float dk1 = lastbin  ? 1.0f : (1e-3f + softplus_fast(softplus_fast(zd_hi))); \
    float ul  = sigmoid_fast(zl_sel);                                            \
    float lam = 0.95f * sigmoid_fast(ul) + 0.025f;                               \
    float rbw = frcp_(in_bw);                                                    \
    float in_delta = in_h * rbw;                                                 \
    float wb = sqrtf(dk * frcp_(dk1));                                           \
    float wc = (lam * dk + (1.0f - lam) * wb * dk1) * frcp_(in_delta);           \
    float ya = in_ch;                                                            \
    float yb = in_h + in_ch;                                                     \
    float yc = ((1.0f - lam) * ya + lam * wb * yb) * frcp_((1.0f - lam) + lam * wb); \
    float theta = (xc - in_cw) * rbw;                                            \
    bool mlt = (theta <= lam);                                                   \
    float num = mlt ? (ya * (lam - theta) + wc * yc * theta)                     \
                    : (wc * yc * (1.0f - theta) + wb * yb * (theta - lam));      \
    float den = mlt ? ((lam - theta) + wc * theta)                               \
                    : (wc * (1.0f - theta) + wb * (theta - lam));                \
    float sout = num * frcp_(den);                                               \
    float dnum = (mlt ? (wc * lam * (yc - ya))                                   \
                      : (wb * wc * (1.0f - lam) * (yb - yc))) * rbw;             \
    float slad = __logf(dnum) - 2.0f * __logf(fabsf(den));                       \
    bool inside = ((xv) >= -20.0f) && ((xv) <= 20.0f);                           \
    out[(giv)] = inside ? sout : (xv);                                           \
    lad[(giv)] = inside ? slad : 0.0f;                                           \
  }

__global__ __launch_bounds__(1024, 4) void spline_mfma(
    const float* __restrict__ xin, const float* __restrict__ cond,
    const float* __restrict__ Ww, const float* __restrict__ bw,
    const float* __restrict__ Wh, const float* __restrict__ bh,
    const float* __restrict__ Wd, const float* __restrict__ bd,
    const float* __restrict__ Wl, const float* __restrict__ bl,
    float* __restrict__ out, float* __restrict__ lad, int N)
{
    __shared__ __align__(16) _Float16 Z[BM * ZSTRIDE];     // 139264 B
    __shared__ __align__(16) _Float16 Blds[16 * 64 * 8];   // 16384 B (total 152 KB <= 160)

    const int tid  = threadIdx.x;
    const int wave = tid >> 6;     // 0..15
    const int lane = tid & 63;
    const int l15  = lane & 15;
    const int lg   = lane >> 4;

    const size_t bRow = (size_t)blockIdx.x * BM;
    const size_t gi = bRow + tid;

    // ---- stage B into LDS (waves 0-3 handle matrices t=0..3), ONE barrier ----
    half8 hz;
    hz[0]=hz[1]=hz[2]=hz[3]=hz[4]=hz[5]=hz[6]=hz[7] = (_Float16)0.0f;
    if (wave < 4) {
        const float* Wt = (wave == 0) ? Ww : (wave == 1) ? Wh : (wave == 2) ? Wl : Wd;
        const bool isWd = (wave == 3);
        STAGE_B_LDS(Wt, isWd)
    }
    __syncthreads();

    // ---- A: 2-buffer rolling prefetch (X/Y) — R10's proven schedule;
    // VGPR budget: 64 A + 16 acc + frags/addr ~= 110 < 128 (16-wave cap) ----
    float4 X0, X1, X2, X3, X4, X5, X6, X7;
    float4 Y0, Y1, Y2, Y3, Y4, Y5, Y6, Y7;
    LOADC(X, CPTR(0))
    LOADC(Y, CPTR(1))
    float x = xin[gi < (size_t)N ? gi : 0];

    const f32x4 zf4 = {0.f, 0.f, 0.f, 0.f};
    f32x4 acc0 = zf4, acc1 = zf4, acc2 = zf4, acc3 = zf4;
    half8 af0, af1, af2, af3;
    _Float16* zbase = &Z[(size_t)(wave * 64 + lg * 4) * ZSTRIDE + l15 * 4];

    GEMM_CHUNK(X, 0)
    LOADC(X, CPTR(2))
    GEMM_CHUNK(Y, 1)
    LOADC(Y, CPTR(3))
    GEMM_CHUNK(X, 2)
    GEMM_CHUNK(Y, 3)

    // Z rows for this thread are wave-local -> lgkm drain only (no barrier)
    FENCE_LDS
    EPILOGUE(x, gi)
}

extern "C" void kernel_launch(void* const* d_in, const int* in_sizes, int n_in,
                              void* d_out, int out_size, void* d_ws, size_t ws_size,
                              hipStream_t stream) {
    const float* xin  = (const float*)d_in[0];
    const float* cond = (const float*)d_in[1];
    const float* Ww   = (const float*)d_in[2];
    const float* bwp  = (const float*)d_in[3];
    const float* Wh   = (const float*)d_in[4];
    const float* bhp  = (const float*)d_in[5];
    const float* Wd   = (const float*)d_in[6];
    const float* bdp  = (const float*)d_in[7];
    const float* Wl   = (const float*)d_in[8];
    const float* blp  = (const float*)d_in[9];
    int N = in_sizes[0];  // 32*8192
    float* out = (float*)d_out;
    float* lad = out + N;
    int grid = (N + BM - 1) / BM;   // 256 blocks = one per CU, 16 waves each
    hipLaunchKernelGGL(spline_mfma, dim3(grid), dim3(1024), 0, stream,
                       xin, cond, Ww, bwp, Wh, bhp, Wd, bdp, Wl, blp, out, lad, N);
}

// Round 15
// 39.353 us; speedup vs baseline: 1.3406x; 1.3406x over previous
//
#include <hip/hip_runtime.h>
#include <math.h>

#define NB 16
#define DM 128
#define BM 256
#define ZSTRIDE 68   // halves per Z row: 136 B (8B-aligned b64 access, bank-spread)

typedef _Float16 half8  __attribute__((ext_vector_type(8)));
typedef _Float16 half4v __attribute__((ext_vector_type(4)));
typedef _Float16 half2v __attribute__((ext_vector_type(2)));
typedef __fp16   fp16x2 __attribute__((ext_vector_type(2)));
typedef float    f32x4  __attribute__((ext_vector_type(4)));

__device__ __forceinline__ float frcp_(float x) { return __builtin_amdgcn_rcpf(x); }
__device__ __forceinline__ float softplus_fast(float x) {
    return fmaxf(x, 0.0f) + __logf(1.0f + __expf(-fabsf(x)));
}
__device__ __forceinline__ float sigmoid_fast(float x) {
    return frcp_(1.0f + __expf(-x));
}
__device__ __forceinline__ void softmax16_m(float* z) {
    float m = z[0];
#pragma unroll
    for (int k = 1; k < NB; k++) m = fmaxf(m, z[k]);
    float s = 0.0f;
#pragma unroll
    for (int k = 0; k < NB; k++) { z[k] = __expf(z[k] - m); s += z[k]; }
    float r = frcp_(s);
#pragma unroll
    for (int k = 0; k < NB; k++) z[k] *= r;
}
// outer softmax: inputs in [0,1] (inner softmax output) -> no max-subtract
__device__ __forceinline__ void softmax16_nm(float* z) {
    float s = 0.0f;
#pragma unroll
    for (int k = 0; k < NB; k++) { z[k] = __expf(z[k]); s += z[k]; }
    float r = frcp_(s);
#pragma unroll
    for (int k = 0; k < NB; k++) z[k] *= r;
}

__device__ __forceinline__ half2v pk_(float lo, float hi) {
    fp16x2 p = __builtin_amdgcn_cvt_pkrtz(lo, hi);
    return __builtin_bit_cast(half2v, p);
}
__device__ __forceinline__ half8 cvt8(float4 a0, float4 a1) {
    half2v p0 = pk_(a0.x, a0.y);
    half2v p1 = pk_(a0.z, a0.w);
    half2v p2 = pk_(a1.x, a1.y);
    half2v p3 = pk_(a1.z, a1.w);
    half8 f;
    f[0] = p0[0]; f[1] = p0[1]; f[2] = p1[0]; f[3] = p1[1];
    f[4] = p2[0]; f[5] = p2[1]; f[6] = p3[0]; f[7] = p3[1];
    return f;
}

// ---- global_load_lds: per-lane GLOBAL src, wave-uniform LDS dest (+lane*16) ----
#define GLL16(g, l)                                                             \
    __builtin_amdgcn_global_load_lds(                                           \
        (const __attribute__((address_space(1))) void*)(g),                     \
        (__attribute__((address_space(3))) void*)(l), 16, 0, 0);

// Issue chunk c's A-tile (16 rows x 512B) as 8 CONTIGUOUS 1KB instructions.
// Instr k covers rows 2k,2k+1; lane i -> row 2k+(i>>5), bytes (i&31)*16.
// Global source pre-swizzled by ((row&7)<<4) so LDS stays linear (m173) but
// frag reads are bank-spread. XOR stays within the row's 512B (bits 4-6).
#define ISSUE_A(c) {                                                            \
    const char* gb_ = (const char*)(cond + (bRow + (size_t)(wave * 64 + (c) * 16)) * DM); \
    _Pragma("unroll")                                                           \
    for (int k_ = 0; k_ < 8; k_++) {                                            \
        const unsigned r_ = 2u * k_ + lsel;                                     \
        const char* ga_ = gb_ + (size_t)r_ * 512 + (cb32 ^ ((r_ & 7u) << 4));   \
        GLL16(ga_, AstageW + k_ * 256)                                          \
    } }

// Read A-frags for the staged chunk: frag s = two float4 at cols
// {128s, 128s+64} (bytes) of row l15, XOR-deswizzled. Slot formula (A==B):
//   frag s, elem e: k = 32s + 16*(e>=4) + lg*4 + (e&3)
#define RDFRAGS                                                                 \
    fA = *(const float4*)(ab + ((128 * 0 + lgb) ^ swz));                        \
    fB = *(const float4*)(ab + ((128 * 0 + 64 + lgb) ^ swz));                   \
    af0 = cvt8(fA, fB);                                                         \
    fA = *(const float4*)(ab + ((128 * 1 + lgb) ^ swz));                        \
    fB = *(const float4*)(ab + ((128 * 1 + 64 + lgb) ^ swz));                   \
    af1 = cvt8(fA, fB);                                                         \
    fA = *(const float4*)(ab + ((128 * 2 + lgb) ^ swz));                        \
    fB = *(const float4*)(ab + ((128 * 2 + 64 + lgb) ^ swz));                   \
    af2 = cvt8(fA, fB);                                                         \
    fA = *(const float4*)(ab + ((128 * 3 + lgb) ^ swz));                        \
    fB = *(const float4*)(ab + ((128 * 3 + 64 + lgb) ^ swz));                   \
    af3 = cvt8(fA, fB);

#define MFMA_S(af, s)                                                           \
    acc0 = __builtin_amdgcn_mfma_f32_16x16x32_f16(af, B0##s, acc0, 0, 0, 0);    \
    acc1 = __builtin_amdgcn_mfma_f32_16x16x32_f16(af, B1##s, acc1, 0, 0, 0);    \
    acc2 = __builtin_amdgcn_mfma_f32_16x16x32_f16(af, B2##s, acc2, 0, 0, 0);    \
    acc3 = __builtin_amdgcn_mfma_f32_16x16x32_f16(af, B3##s, acc3, 0, 0, 0);

// D layout: col = lane&15, row = (lane>>4)*4 + reg  [m89/m91]
// interleaved Z: pos = col*4 + t  <=>  net n = t*16 + col
#define STOREZ(c) {                                                             \
    _Float16* zpw = zbase + (size_t)((c) * 16) * ZSTRIDE;                       \
    _Pragma("unroll")                                                           \
    for (int r = 0; r < 4; r++) {                                               \
        half2v p0 = pk_(acc0[r], acc1[r]);                                      \
        half2v p1 = pk_(acc2[r], acc3[r]);                                      \
        half4v w; w[0] = p0[0]; w[1] = p0[1]; w[2] = p1[0]; w[3] = p1[1];       \
        *(half4v*)(zpw + (size_t)r * ZSTRIDE) = w;                              \
    } }

#define RESET_ACC  acc0 = zf4; acc1 = zf4; acc2 = zf4; acc3 = zf4;

// B frag staging into VGPRs (R8-proven): row l15 of Wt, full-line offsets,
// identical slot formula as A.
#define STAGE_B(Wt, isWd, Q0, Q1, Q2, Q3) {                                     \
    const bool val = (!(isWd)) || (l15 < 15);                                   \
    const float* srcl = (Wt) + (size_t)(val ? l15 : 0) * DM + lg * 4;           \
    float4 q0 = *(const float4*)(srcl + 0),  q1 = *(const float4*)(srcl + 16);  \
    float4 q2 = *(const float4*)(srcl + 32), q3 = *(const float4*)(srcl + 48);  \
    float4 q4 = *(const float4*)(srcl + 64), q5 = *(const float4*)(srcl + 80);  \
    float4 q6 = *(const float4*)(srcl + 96), q7 = *(const float4*)(srcl + 112); \
    Q0 = val ? cvt8(q0, q1) : hz;                                               \
    Q1 = val ? cvt8(q2, q3) : hz;                                               \
    Q2 = val ? cvt8(q4, q5) : hz;                                               \
    Q3 = val ? cvt8(q6, q7) : hz; }

// rule #18: inline-asm waits need sched_barrier fencing on both sides
#define FENCE_VM                                        \
    __builtin_amdgcn_sched_barrier(0);                  \
    asm volatile("s_waitcnt vmcnt(0)" ::: "memory");    \
    __builtin_amdgcn_sched_barrier(0);
#define FENCE_LDS                                       \
    __builtin_amdgcn_sched_barrier(0);                  \
    asm volatile("s_waitcnt lgkmcnt(0)" ::: "memory");  \
    __builtin_amdgcn_sched_barrier(0);

// ---- full spline epilogue for one row (R8/R10/R11's proven version) ----
#define EPILOGUE(xv, giv)                                                        \
  if ((giv) < (size_t)N) {                                                       \
    float zw[NB], zh[NB], zl[NB], zd[NB - 1];                                    \
    const half4v* zr4 = (const half4v*)&Z[(size_t)tid * ZSTRIDE];                \
    _Pragma("unroll")                                                            \
    for (int j = 0; j < NB; j++) {                                               \
        half4v v = zr4[j];                                                       \
        zw[j] = (float)v[0] + bw[j];                                             \
        zh[j] = (float)v[1] + bh[j];                                             \
        zl[j] = (float)v[2] + bl[j];                                             \
        if (j < NB - 1) zd[j] = (float)v[3] + bd[j];                             \
    }                                                                            \
    float xc = fminf(fmaxf((xv), -20.0f), 20.0f);                                \
    softmax16_m(zw);                                                             \
    softmax16_nm(zw);                                                            \
    const float scale = (1.0f - 1e-3f * NB);                                     \
    float cw[NB + 1];                                                            \
    cw[0] = -20.0f;                                                              \
    float cum = 0.0f;                                                            \
    _Pragma("unroll")                                                            \
    for (int k = 0; k < NB; k++) {                                               \
        cum += 1e-3f + scale * zw[k];                                            \
        cw[k + 1] = 40.0f * cum - 20.0f;                                         \
    }                                                                            \
    cw[NB] = 20.0f;                                                              \
    softmax16_m(zh);                                                             \
    softmax16_nm(zh);                                                            \
    float ch[NB + 1];                                                            \
    ch[0] = -20.0f;                                                              \
    cum = 0.0f;                                                                  \
    _Pragma("unroll")                                                            \
    for (int k = 0; k < NB; k++) {                                               \
        cum += 1e-3f + scale * zh[k];                                            \
        ch[k + 1] = 40.0f * cum - 20.0f;                                         \
    }                                                                            \
    ch[NB] = 20.0f;                                                              \
    float in_cw = cw[0], cw_hi = cw[1], in_ch = ch[0], ch_hi = ch[1];            \
    float zl_sel = zl[0], zd_lo = zd[0], zd_hi = zd[0];                          \
    _Pragma("unroll")                                                            \
    for (int k = 1; k < NB; k++) {                                               \
        bool take = (xc >= cw[k]);                                               \
        in_cw  = take ? cw[k]     : in_cw;                                       \
        cw_hi  = take ? cw[k + 1] : cw_hi;                                       \
        in_ch  = take ? ch[k]     : in_ch;                                       \
        ch_hi  = take ? ch[k + 1] : ch_hi;                                       \
        zl_sel = take ? zl[k]     : zl_sel;                                      \
        zd_lo  = take ? zd[k - 1] : zd_lo;                                       \
        zd_hi  = take ? zd[(k < NB - 1) ? k : NB - 2] : zd_hi;                   \
    }                                                                            \
    bool firstbin = (xc <  cw[1]);                                               \
    bool lastbin  = (xc >= cw[NB - 1]);                                          \
    float in_bw = cw_hi - in_cw;                                                 \
    float in_h  = ch_hi - in_ch;                                                 \
    float dk  = firstbin ? 1.0f : (1e-3f + softplus_fast(softplus_fast(zd_lo))); \
    float dk1 = lastbin  ? 1.0f : (1e-3f + softplus_fast(softplus_fast(zd_hi))); \
    float ul  = sigmoid_fast(zl_sel);                                            \
    float lam = 0.95f * sigmoid_fast(ul) + 0.025f;                               \
    float rbw = frcp_(in_bw);                                                    \
    float in_delta = in_h * rbw;                                                 \
    float wb = sqrtf(dk * frcp_(dk1));                                           \
    float wc = (lam * dk + (1.0f - lam) * wb * dk1) * frcp_(in_delta);           \
    float ya = in_ch;                                                            \
    float yb = in_h + in_ch;                                                     \
    float yc = ((1.0f - lam) * ya + lam * wb * yb) * frcp_((1.0f - lam) + lam * wb); \
    float theta = (xc - in_cw) * rbw;                                            \
    bool mlt = (theta <= lam);                                                   \
    float num = mlt ? (ya * (lam - theta) + wc * yc * theta)                     \
                    : (wc * yc * (1.0f - theta) + wb * yb * (theta - lam));      \
    float den = mlt ? ((lam - theta) + wc * theta)                               \
                    : (wc * (1.0f - theta) + wb * (theta - lam));                \
    float sout = num * frcp_(den);                                               \
    float dnum = (mlt ? (wc * lam * (yc - ya))                                   \
                      : (wb * wc * (1.0f - lam) * (yb - yc))) * rbw;             \
    float slad = __logf(dnum) - 2.0f * __logf(fabsf(den));                       \
    bool inside = ((xv) >= -20.0f) && ((xv) <= 20.0f);                           \
    out[(giv)] = inside ? sout : (xv);                                           \
    lad[(giv)] = inside ? slad : 0.0f;                                           \
  }

__global__ __launch_bounds__(256, 2) void spline_mfma(
    const float* __restrict__ xin, const float* __restrict__ cond,
    const float* __restrict__ Ww, const float* __restrict__ bw,
    const float* __restrict__ Wh, const float* __restrict__ bh,
    const float* __restrict__ Wd, const float* __restrict__ bd,
    const float* __restrict__ Wl, const float* __restrict__ bl,
    float* __restrict__ out, float* __restrict__ lad, int N)
{
    __shared__ __align__(16) _Float16 Z[BM * ZSTRIDE];   // 34816 B
    __shared__ __align__(16) float Astage[4 * 2048];     // 4 waves x 8 KB = 32768 B

    const int tid  = threadIdx.x;
    const int wave = tid >> 6;
    const int lane = tid & 63;
    const int l15  = lane & 15;
    const int lg   = lane >> 4;
    const unsigned lsel = (unsigned)(lane >> 5);          // which row of the pair
    const unsigned cb32 = (unsigned)((lane & 31) * 16);   // byte within row

    const size_t bRow = (size_t)blockIdx.x * BM;          // N % BM == 0 (262144/256)
    const size_t gi = bRow + tid;

    // ---- B into VGPRs, per wave (no __syncthreads in this kernel) ----
    half8 hz;
    hz[0]=hz[1]=hz[2]=hz[3]=hz[4]=hz[5]=hz[6]=hz[7] = (_Float16)0.0f;
    half8 B00, B01, B02, B03, B10, B11, B12, B13,
          B20, B21, B22, B23, B30, B31, B32, B33;
    STAGE_B(Ww, false, B00, B01, B02, B03)
    STAGE_B(Wh, false, B10, B11, B12, B13)
    STAGE_B(Wl, false, B20, B21, B22, B23)
    STAGE_B(Wd, true,  B30, B31, B32, B33)

    float* AstageW = Astage + wave * 2048;                // wave-private 8 KB

    // prologue: chunk 0 in flight (contiguous 1KB/instruction)
    ISSUE_A(0)
    float x = xin[gi < (size_t)N ? gi : 0];

    const f32x4 zf4 = {0.f, 0.f, 0.f, 0.f};
    f32x4 acc0 = zf4, acc1 = zf4, acc2 = zf4, acc3 = zf4;
    half8 af0, af1, af2, af3;
    float4 fA, fB;
    _Float16* zbase = &Z[(size_t)(wave * 64 + lg * 4) * ZSTRIDE + l15 * 4];
    const char* ab = (const char*)AstageW + l15 * 512;
    const unsigned swz = (unsigned)((l15 & 7) << 4);
    const unsigned lgb = (unsigned)(lg * 16);

    // ---- chunk 0 ----
    FENCE_VM          // A-stage resident
    RDFRAGS
    FENCE_LDS         // frag reads retired -> safe to overwrite stage
    ISSUE_A(1)
    MFMA_S(af0, 0) MFMA_S(af1, 1) MFMA_S(af2, 2) MFMA_S(af3, 3)
    STOREZ(0) RESET_ACC
    // ---- chunk 1 ----
    FENCE_VM
    RDFRAGS
    FENCE_LDS
    ISSUE_A(2)
    MFMA_S(af0, 0) MFMA_S(af1, 1) MFMA_S(af2, 2) MFMA_S(af3, 3)
    STOREZ(1) RESET_ACC
    // ---- chunk 2 ----
    FENCE_VM
    RDFRAGS
    FENCE_LDS
    ISSUE_A(3)
    MFMA_S(af0, 0) MFMA_S(af1, 1) MFMA_S(af2, 2) MFMA_S(af3, 3)
    STOREZ(2) RESET_ACC
    // ---- chunk 3 ----
    FENCE_VM
    RDFRAGS
    MFMA_S(af0, 0) MFMA_S(af1, 1) MFMA_S(af2, 2) MFMA_S(af3, 3)
    STOREZ(3)

    // Z rows for this thread are wave-local -> lgkm drain only (no barrier)
    FENCE_LDS
    EPILOGUE(x, gi)
}

extern "C" void kernel_launch(void* const* d_in, const int* in_sizes, int n_in,
                              void* d_out, int out_size, void* d_ws, size_t ws_size,
                              hipStream_t stream) {
    const float* xin  = (const float*)d_in[0];
    const float* cond = (const float*)d_in[1];
    const float* Ww   = (const float*)d_in[2];
    const float* bwp  = (const float*)d_in[3];
    const float* Wh   = (const float*)d_in[4];
    const float* bhp  = (const float*)d_in[5];
    const float* Wd   = (const float*)d_in[6];
    const float* bdp  = (const float*)d_in[7];
    const float* Wl   = (const float*)d_in[8];
    const float* blp  = (const float*)d_in[9];
    int N = in_sizes[0];  // 32*8192; N % BM == 0
    float* out = (float*)d_out;
    float* lad = out + N;
    int grid = (N + BM - 1) / BM;   // 1024 blocks; 2 resident/CU (LDS-bound)
    hipLaunchKernelGGL(spline_mfma, dim3(grid), dim3(256), 0, stream,
                       xin, cond, Ww, bwp, Wh, bhp, Wd, bdp, Wl, blp, out, lad, N);
}

// Round 16
// 33.406 us; speedup vs baseline: 1.5792x; 1.1780x over previous
//
#include <hip/hip_runtime.h>
#include <math.h>

#define NB 16
#define DM 128
#define BM 256
#define ZSTRIDE 68   // halves per Z row: 136 B (8B-aligned b64 access, bank-spread)

typedef _Float16 half8  __attribute__((ext_vector_type(8)));
typedef _Float16 half4v __attribute__((ext_vector_type(4)));
typedef _Float16 half2v __attribute__((ext_vector_type(2)));
typedef __fp16   fp16x2 __attribute__((ext_vector_type(2)));
typedef float    f32x4  __attribute__((ext_vector_type(4)));

__device__ __forceinline__ float frcp_(float x) { return __builtin_amdgcn_rcpf(x); }
__device__ __forceinline__ float softplus_fast(float x) {
    return fmaxf(x, 0.0f) + __logf(1.0f + __expf(-fabsf(x)));
}
__device__ __forceinline__ float sigmoid_fast(float x) {
    return frcp_(1.0f + __expf(-x));
}
__device__ __forceinline__ void softmax16_m(float* z) {
    float m = z[0];
#pragma unroll
    for (int k = 1; k < NB; k++) m = fmaxf(m, z[k]);
    float s = 0.0f;
#pragma unroll
    for (int k = 0; k < NB; k++) { z[k] = __expf(z[k] - m); s += z[k]; }
    float r = frcp_(s);
#pragma unroll
    for (int k = 0; k < NB; k++) z[k] *= r;
}
// outer softmax: inputs in [0,1] (inner softmax output) -> no max-subtract
__device__ __forceinline__ void softmax16_nm(float* z) {
    float s = 0.0f;
#pragma unroll
    for (int k = 0; k < NB; k++) { z[k] = __expf(z[k]); s += z[k]; }
    float r = frcp_(s);
#pragma unroll
    for (int k = 0; k < NB; k++) z[k] *= r;
}

__device__ __forceinline__ half2v pk_(float lo, float hi) {
    fp16x2 p = __builtin_amdgcn_cvt_pkrtz(lo, hi);
    return __builtin_bit_cast(half2v, p);
}
__device__ __forceinline__ half8 cvt8(float4 a0, float4 a1) {
    half2v p0 = pk_(a0.x, a0.y);
    half2v p1 = pk_(a0.z, a0.w);
    half2v p2 = pk_(a1.x, a1.y);
    half2v p3 = pk_(a1.z, a1.w);
    half8 f;
    f[0] = p0[0]; f[1] = p0[1]; f[2] = p1[0]; f[3] = p1[1];
    f[4] = p2[0]; f[5] = p2[1]; f[6] = p3[0]; f[7] = p3[1];
    return f;
}

// ---- named-variable macros (NO addressable aggregates; rule #20) ----
// Full-line pattern: instruction j reads 16 rows x one FULL 64B line each.
// Fragment slot formula (A and B IDENTICAL => HW k-permutation cancels):
//   frag s, elem e: k = 32s + 16*(e>=4) + lg*4 + (e&3)
#define LOADC(P, cr)                                    \
    P##0 = *(const float4*)((cr) + 0);                  \
    P##1 = *(const float4*)((cr) + 16);                 \
    P##2 = *(const float4*)((cr) + 32);                 \
    P##3 = *(const float4*)((cr) + 48);                 \
    P##4 = *(const float4*)((cr) + 64);                 \
    P##5 = *(const float4*)((cr) + 80);                 \
    P##6 = *(const float4*)((cr) + 96);                 \
    P##7 = *(const float4*)((cr) + 112);

#define CVTC(P)                                         \
    af0 = cvt8(P##0, P##1);                             \
    af1 = cvt8(P##2, P##3);                             \
    af2 = cvt8(P##4, P##5);                             \
    af3 = cvt8(P##6, P##7);

// B frags live in LDS, fragment-major: frag (t,s) of lane at
// byte offset ((t*4+s)*64 + lane)*16 -> one ds_read_b128, 2-way aliasing (free)
#define MFMA_GRP(af, s) {                                                       \
    const half8 bt0 = *(const half8*)(Blds + (((0*4+(s))*64 + lane) * 8));      \
    const half8 bt1 = *(const half8*)(Blds + (((1*4+(s))*64 + lane) * 8));      \
    const half8 bt2 = *(const half8*)(Blds + (((2*4+(s))*64 + lane) * 8));      \
    const half8 bt3 = *(const half8*)(Blds + (((3*4+(s))*64 + lane) * 8));      \
    acc0 = __builtin_amdgcn_mfma_f32_16x16x32_f16(af, bt0, acc0, 0, 0, 0);      \
    acc1 = __builtin_amdgcn_mfma_f32_16x16x32_f16(af, bt1, acc1, 0, 0, 0);      \
    acc2 = __builtin_amdgcn_mfma_f32_16x16x32_f16(af, bt2, acc2, 0, 0, 0);      \
    acc3 = __builtin_amdgcn_mfma_f32_16x16x32_f16(af, bt3, acc3, 0, 0, 0);      \
}

// D layout: col = lane&15, row = (lane>>4)*4 + reg  [m89/m91]
// interleaved Z: pos = col*4 + t  <=>  net n = t*16 + col
#define STOREZ(c) {                                                             \
    _Float16* zpw = zbase + (size_t)((c) * 16) * ZSTRIDE;                       \
    _Pragma("unroll")                                                           \
    for (int r = 0; r < 4; r++) {                                               \
        half2v p0 = pk_(acc0[r], acc1[r]);                                      \
        half2v p1 = pk_(acc2[r], acc3[r]);                                      \
        half4v w; w[0] = p0[0]; w[1] = p0[1]; w[2] = p1[0]; w[3] = p1[1];       \
        *(half4v*)(zpw + (size_t)r * ZSTRIDE) = w;                              \
    } }

#define RESET_ACC  acc0 = zf4; acc1 = zf4; acc2 = zf4; acc3 = zf4;

#define GEMM_CHUNK(P, c)                                                        \
    CVTC(P)                                                                     \
    MFMA_GRP(af0, 0) MFMA_GRP(af1, 1) MFMA_GRP(af2, 2) MFMA_GRP(af3, 3)         \
    STOREZ(c) RESET_ACC

// B staging: wave w computes frags of matrix t=w (row l15, full-line offsets,
// identical slot formula as A) and parks them in LDS fragment-major.
#define STAGE_B_LDS(Wt, isWd) {                                                 \
    const bool val = (!(isWd)) || (l15 < 15);                                   \
    const float* srcl = (Wt) + (size_t)(val ? l15 : 0) * DM + lg * 4;           \
    float4 q0 = *(const float4*)(srcl + 0),  q1 = *(const float4*)(srcl + 16);  \
    float4 q2 = *(const float4*)(srcl + 32), q3 = *(const float4*)(srcl + 48);  \
    float4 q4 = *(const float4*)(srcl + 64), q5 = *(const float4*)(srcl + 80);  \
    float4 q6 = *(const float4*)(srcl + 96), q7 = *(const float4*)(srcl + 112); \
    half8 Q0 = val ? cvt8(q0, q1) : hz;                                         \
    half8 Q1 = val ? cvt8(q2, q3) : hz;                                         \
    half8 Q2 = val ? cvt8(q4, q5) : hz;                                         \
    half8 Q3 = val ? cvt8(q6, q7) : hz;                                         \
    *(half8*)(Blds + (((wave*4+0)*64 + lane) * 8)) = Q0;                        \
    *(half8*)(Blds + (((wave*4+1)*64 + lane) * 8)) = Q1;                        \
    *(half8*)(Blds + (((wave*4+2)*64 + lane) * 8)) = Q2;                        \
    *(half8*)(Blds + (((wave*4+3)*64 + lane) * 8)) = Q3;                        \
}

// rule #18: inline-asm lgkm drain needs sched_barrier fencing
#define FENCE_LDS                                       \
    __builtin_amdgcn_sched_barrier(0);                  \
    asm volatile("s_waitcnt lgkmcnt(0)" ::: "memory");  \
    __builtin_amdgcn_sched_barrier(0);

// clamped row pointer for chunk c of this block's tile
#define CPTR(c) (cond + (((bRow + (size_t)(wave * 64 + (c) * 16 + l15)) < (size_t)N) \
                    ? (bRow + (size_t)(wave * 64 + (c) * 16 + l15))                  \
                    : ((size_t)N - 1)) * DM + lg * 4)

// ---- full spline epilogue for one row (R8/R10/R11's proven version) ----
#define EPILOGUE(xv, giv)                                                        \
  if ((giv) < (size_t)N) {                                                       \
    float zw[NB], zh[NB], zl[NB], zd[NB - 1];                                    \
    const half4v* zr4 = (const half4v*)&Z[(size_t)tid * ZSTRIDE];                \
    _Pragma("unroll")                                                            \
    for (int j = 0; j < NB; j++) {                                               \
        half4v v = zr4[j];                                                       \
        zw[j] = (float)v[0] + bw[j];                                             \
        zh[j] = (float)v[1] + bh[j];                                             \
        zl[j] = (float)v[2] + bl[j];                                             \
        if (j < NB - 1) zd[j] = (float)v[3] + bd[j];                             \
    }                                                                            \
    float xc = fminf(fmaxf((xv), -20.0f), 20.0f);                                \
    softmax16_m(zw);                                                             \
    softmax16_nm(zw);                                                            \
    const float scale = (1.0f - 1e-3f * NB);                                     \
    float cw[NB + 1];                                                            \
    cw[0] = -20.0f;                                                              \
    float cum = 0.0f;                                                            \
    _Pragma("unroll")                                                            \
    for (int k = 0; k < NB; k++) {                                               \
        cum += 1e-3f + scale * zw[k];                                            \
        cw[k + 1] = 40.0f * cum - 20.0f;                                         \
    }                                                                            \
    cw[NB] = 20.0f;                                                              \
    softmax16_m(zh);                                                             \
    softmax16_nm(zh);                                                            \
    float ch[NB + 1];                                                            \
    ch[0] = -20.0f;                                                              \
    cum = 0.0f;                                                                  \
    _Pragma("unroll")                                                            \
    for (int k = 0; k < NB; k++) {                                               \
        cum += 1e-3f + scale * zh[k];                                            \
        ch[k + 1] = 40.0f * cum - 20.0f;                                         \
    }                                                                            \
    ch[NB] = 20.0f;                                                              \
    float in_cw = cw[0], cw_hi = cw[1], in_ch = ch[0], ch_hi = ch[1];            \
    float zl_sel = zl[0], zd_lo = zd[0], zd_hi = zd[0];                          \
    _Pragma("unroll")                                                            \
    for (int k = 1; k < NB; k++) {                                               \
        bool take = (xc >= cw[k]);                                               \
        in_cw  = take ? cw[k]     : in_cw;                                       \
        cw_hi  = take ? cw[k + 1] : cw_hi;                                       \
        in_ch  = take ? ch[k]     : in_ch;                                       \
        ch_hi  = take ? ch[k + 1] : ch_hi;                                       \
        zl_sel = take ? zl[k]     : zl_sel;                                      \
        zd_lo  = take ? zd[k - 1] : zd_lo;                                       \
        zd_hi  = take ? zd[(k < NB - 1) ? k : NB - 2] : zd_hi;                   \
    }                                                                            \
    bool firstbin = (xc <  cw[1]);                                               \
    bool lastbin  = (xc >= cw[NB - 1]);                                          \
    float in_bw = cw_hi - in_cw;                                                 \
    float in_h  = ch_hi - in_ch;                                                 \
    float dk  = firstbin ? 1.0f : (1e-3f + softplus_fast(softplus_fast(zd_lo))); \
    float dk1 = lastbin  ? 1.0f : (1e-3f + softplus_fast(softplus_fast(zd_hi))); \
    float ul  = sigmoid_fast(zl_sel);                                            \
    float lam = 0.95f * sigmoid_fast(ul) + 0.025f;                               \
    float rbw = frcp_(in_bw);                                                    \
    float in_delta = in_h * rbw;                                                 \
    float wb = sqrtf(dk * frcp_(dk1));                                           \
    float wc = (lam * dk + (1.0f - lam) * wb * dk1) * frcp_(in_delta);           \
    float ya = in_ch;                                                            \
    float yb = in_h + in_ch;                                                     \
    float yc = ((1.0f - lam) * ya + lam * wb * yb) * frcp_((1.0f - lam) + lam * wb); \
    float theta = (xc - in_cw) * rbw;                                            \
    bool mlt = (theta <= lam);                                                   \
    float num = mlt ? (ya * (lam - theta) + wc * yc * theta)                     \
                    : (wc * yc * (1.0f - theta) + wb * yb * (theta - lam));      \
    float den = mlt ? ((lam - theta) + wc * theta)                               \
                    : (wc * (1.0f - theta) + wb * (theta - lam));                \
    float sout = num * frcp_(den);                                               \
    float dnum = (mlt ? (wc * lam * (yc - ya))                                   \
                      : (wb * wc * (1.0f - lam) * (yb - yc))) * rbw;             \
    float slad = __logf(dnum) - 2.0f * __logf(fabsf(den));                       \
    bool inside = ((xv) >= -20.0f) && ((xv) <= 20.0f);                           \
    out[(giv)] = inside ? sout : (xv);                                           \
    lad[(giv)] = inside ? slad : 0.0f;                                           \
  }

__global__ __launch_bounds__(256, 3) void spline_mfma(
    const float* __restrict__ xin, const float* __restrict__ cond,
    const float* __restrict__ Ww, const float* __restrict__ bw,
    const float* __restrict__ Wh, const float* __restrict__ bh,
    const float* __restrict__ Wd, const float* __restrict__ bd,
    const float* __restrict__ Wl, const float* __restrict__ bl,
    float* __restrict__ out, float* __restrict__ lad, int N)
{
    __shared__ __align__(16) _Float16 Z[BM * ZSTRIDE];     // 34816 B
    __shared__ __align__(16) _Float16 Blds[16 * 64 * 8];   // 16384 B

    const int tid  = threadIdx.x;
    const int wave = tid >> 6;
    const int lane = tid & 63;
    const int l15  = lane & 15;
    const int lg   = lane >> 4;

    const size_t bRow = (size_t)blockIdx.x * BM;
    const size_t gi = bRow + tid;

    // ---- stage B into LDS (wave w handles matrix t=w), then ONE barrier.
    // All B global loads are consumed before the barrier, so the barrier's
    // implicit vmcnt(0) drain is a no-op; A-loads issue after it.
    half8 hz;
    hz[0]=hz[1]=hz[2]=hz[3]=hz[4]=hz[5]=hz[6]=hz[7] = (_Float16)0.0f;
    {
        const float* Wt = (wave == 0) ? Ww : (wave == 1) ? Wh : (wave == 2) ? Wl : Wd;
        const bool isWd = (wave == 3);
        STAGE_B_LDS(Wt, isWd)
    }
    __syncthreads();

    // ---- A: full 4-chunk burst prefetch (32 dwordx4 back-to-back: one HBM
    // latency exposure, 32 KB/wave outstanding; consumption waits incremental)
    float4 A0_0, A0_1, A0_2, A0_3, A0_4, A0_5, A0_6, A0_7;
    float4 A1_0, A1_1, A1_2, A1_3, A1_4, A1_5, A1_6, A1_7;
    float4 A2_0, A2_1, A2_2, A2_3, A2_4, A2_5, A2_6, A2_7;
    float4 A3_0, A3_1, A3_2, A3_3, A3_4, A3_5, A3_6, A3_7;
    LOADC(A0_, CPTR(0))
    LOADC(A1_, CPTR(1))
    LOADC(A2_, CPTR(2))
    LOADC(A3_, CPTR(3))
    float x = xin[gi < (size_t)N ? gi : 0];

    const f32x4 zf4 = {0.f, 0.f, 0.f, 0.f};
    f32x4 acc0 = zf4, acc1 = zf4, acc2 = zf4, acc3 = zf4;
    half8 af0, af1, af2, af3;
    _Float16* zbase = &Z[(size_t)(wave * 64 + lg * 4) * ZSTRIDE + l15 * 4];

    GEMM_CHUNK(A0_, 0)
    GEMM_CHUNK(A1_, 1)
    GEMM_CHUNK(A2_, 2)
    GEMM_CHUNK(A3_, 3)

    // Z rows for this thread are wave-local -> lgkm drain only (no barrier)
    FENCE_LDS
    EPILOGUE(x, gi)
}

extern "C" void kernel_launch(void* const* d_in, const int* in_sizes, int n_in,
                              void* d_out, int out_size, void* d_ws, size_t ws_size,
                              hipStream_t stream) {
    const float* xin  = (const float*)d_in[0];
    const float* cond = (const float*)d_in[1];
    const float* Ww   = (const float*)d_in[2];
    const float* bwp  = (const float*)d_in[3];
    const float* Wh   = (const float*)d_in[4];
    const float* bhp  = (const float*)d_in[5];
    const float* Wd   = (const float*)d_in[6];
    const float* bdp  = (const float*)d_in[7];
    const float* Wl   = (const float*)d_in[8];
    const float* blp  = (const float*)d_in[9];
    int N = in_sizes[0];  // 32*8192
    float* out = (float*)d_out;
    float* lad = out + N;
    int grid = (N + BM - 1) / BM;   // one tile per block; 3 blocks/CU resident
    hipLaunchKernelGGL(spline_mfma, dim3(grid), dim3(256), 0, stream,
                       xin, cond, Ww, bwp, Wh, bhp, Wd, bdp, Wl, blp, out, lad, N);
}